// Round 6
// baseline (4086.108 us; speedup 1.0000x reference)
//
#include <hip/hip_runtime.h>

// Problem dims
#define B_ 32
#define S_ 512
#define D_ 512
#define H_ 256

typedef float floatx4 __attribute__((ext_vector_type(4)));
typedef short short8v __attribute__((ext_vector_type(8)));
typedef _Float16 half8v __attribute__((ext_vector_type(8)));
typedef unsigned short u16;
typedef unsigned int u32;
typedef unsigned long long u64;
typedef u32 u32x4 __attribute__((ext_vector_type(4)));

#define WS_NEEDED 138575872ull

__device__ __forceinline__ u16 f2bf(float f) {
  u32 x = __float_as_uint(f);
  x += 0x7fffu + ((x >> 16) & 1u);   // RNE
  return (u16)(x >> 16);
}
__device__ __forceinline__ float bf2f(u16 h) {
  return __uint_as_float(((u32)h) << 16);
}
__device__ __forceinline__ float decode_hl(u32 v) {
  return bf2f((u16)(v >> 16)) + bf2f((u16)(v & 0xffffu));
}
__device__ __forceinline__ u16 f2h(float f) {     // f32 -> fp16 bits (RNE)
  union { _Float16 h; u16 u; } cv; cv.h = (_Float16)f; return cv.u;
}
__device__ __forceinline__ float sigf(float x) {
  return 1.0f / (1.0f + __expf(-x));
}
__device__ __forceinline__ float tanh_f(float x) {
  float e = __expf(-2.0f * fabsf(x));
  float r = (1.0f - e) / (1.0f + e);
  return copysignf(r, x);
}
// LLC-visible 8B store (v3-proven: full-line-forming across the wave).
__device__ __forceinline__ void store8_cc(u32* p, u64 v) {
  asm volatile("global_store_dwordx2 %0, %1, off sc0 sc1"
               :: "v"(p), "v"(v) : "memory");
}
// 32B poll, LLC-served (sc0 sc1 — same visibility class as agent atomics; proven v3/v5).
__device__ __forceinline__ void poll8_llc(const u32* p, u32x4& a, u32x4& b) {
  asm volatile("global_load_dwordx4 %0, %2, off sc0 sc1\n\t"
               "global_load_dwordx4 %1, %2, off offset:16 sc0 sc1\n\t"
               "s_waitcnt vmcnt(0)"
               : "=&v"(a), "=&v"(b) : "v"(p) : "memory");
}
__device__ __forceinline__ bool match8(u32x4 a, u32x4 b, u32 want) {
  return ((a[0] & 0xffffu) == want) && ((a[1] & 0xffffu) == want)
      && ((a[2] & 0xffffu) == want) && ((a[3] & 0xffffu) == want)
      && ((b[0] & 0xffffu) == want) && ((b[1] & 0xffffu) == want)
      && ((b[2] & 0xffffu) == want) && ((b[3] & 0xffffu) == want);
}

struct alignas(16) U16x8 { u16 v[8]; };

// ---------------- embedding -> X0 bf16, time-major (m = s*32+b, 512 feats) ----------------
__global__ void prep_k(const int* __restrict__ ids, const int* __restrict__ amask,
                       const float* __restrict__ emb, u16* __restrict__ X0) {
  int m = blockIdx.x;            // m = s*32 + b
  int lane = threadIdx.x;        // 64
  int s = m >> 5, b = m & 31;
  int id = ids[b * S_ + s];
  int mk = amask[b * S_ + s];
  const float4* src = (const float4*)(emb + (size_t)id * D_) + lane * 2;
  float4 v0 = src[0], v1 = src[1];
  if (!mk) { v0 = make_float4(0,0,0,0); v1 = make_float4(0,0,0,0); }
  U16x8 o;
  o.v[0]=f2bf(v0.x); o.v[1]=f2bf(v0.y); o.v[2]=f2bf(v0.z); o.v[3]=f2bf(v0.w);
  o.v[4]=f2bf(v1.x); o.v[5]=f2bf(v1.y); o.v[6]=f2bf(v1.z); o.v[7]=f2bf(v1.w);
  *(U16x8*)(X0 + (size_t)m * D_ + lane * 8) = o;
}

// ---------------- fp32 -> bf16 weight convert (w_ih, 2*2*1024*512 elems) ----------------
__global__ void conv_k(const float* __restrict__ w, u16* __restrict__ wbf, int n8) {
  int idx = blockIdx.x * blockDim.x + threadIdx.x;
  if (idx >= n8) return;
  const float4* s = (const float4*)w + (size_t)idx * 2;
  float4 v0 = s[0], v1 = s[1];
  U16x8 o;
  o.v[0]=f2bf(v0.x); o.v[1]=f2bf(v0.y); o.v[2]=f2bf(v0.z); o.v[3]=f2bf(v0.w);
  o.v[4]=f2bf(v1.x); o.v[5]=f2bf(v1.y); o.v[6]=f2bf(v1.z); o.v[7]=f2bf(v1.w);
  *(U16x8*)(wbf + (size_t)idx * 8) = o;
}

// ---------------- zero loss ----------------
__global__ void zero_k(float* __restrict__ loss) {
  if (threadIdx.x == 0) *loss = 0.f;
}

// ---------------- poison the exchange region (tags can never match 0xAAAA) ----------------
__global__ void poison_k(u32* __restrict__ p) {
  const int i = (blockIdx.x * blockDim.x + threadIdx.x) * 4;
  uint4 v = make_uint4(0xAAAAAAAAu, 0xAAAAAAAAu, 0xAAAAAAAAu, 0xAAAAAAAAu);
  *(uint4*)(p + i) = v;
}

// ---------------- bf16 MFMA GEMM: G[m][n] = A[m][:] . W[n][:] + bih[n] + bhh[n] ----------------
__global__ void gemm_k(const u16* __restrict__ A, const u16* __restrict__ W,
                       const float* __restrict__ bih, const float* __restrict__ bhh,
                       u16* __restrict__ G) {
  __shared__ short Asm[64 * 40];
  __shared__ short Bsm[64 * 40];
  const int tid = threadIdx.x;
  const int m0 = blockIdx.x * 64, n0 = blockIdx.y * 64;
  const int wid = tid >> 6, lane = tid & 63;
  const int quad = lane >> 4, lr = lane & 15;
  const int wm = (wid >> 1) * 32, wn = (wid & 1) * 32;
  const int lrow = tid >> 2, lk = (tid & 3) * 8;
  floatx4 acc00 = {0,0,0,0}, acc01 = {0,0,0,0}, acc10 = {0,0,0,0}, acc11 = {0,0,0,0};
  for (int kt = 0; kt < 16; ++kt) {
    const int k0 = kt * 32;
    uint4 av = *(const uint4*)(A + (size_t)(m0 + lrow) * 512 + k0 + lk);
    uint4 bv = *(const uint4*)(W + (size_t)(n0 + lrow) * 512 + k0 + lk);
    __syncthreads();
    *(uint4*)&Asm[lrow * 40 + lk] = av;
    *(uint4*)&Bsm[lrow * 40 + lk] = bv;
    __syncthreads();
    short8v a0 = *(const short8v*)&Asm[(wm + lr) * 40 + quad * 8];
    short8v a1 = *(const short8v*)&Asm[(wm + 16 + lr) * 40 + quad * 8];
    short8v b0 = *(const short8v*)&Bsm[(wn + lr) * 40 + quad * 8];
    short8v b1 = *(const short8v*)&Bsm[(wn + 16 + lr) * 40 + quad * 8];
    acc00 = __builtin_amdgcn_mfma_f32_16x16x32_bf16(a0, b0, acc00, 0, 0, 0);
    acc01 = __builtin_amdgcn_mfma_f32_16x16x32_bf16(a0, b1, acc01, 0, 0, 0);
    acc10 = __builtin_amdgcn_mfma_f32_16x16x32_bf16(a1, b0, acc10, 0, 0, 0);
    acc11 = __builtin_amdgcn_mfma_f32_16x16x32_bf16(a1, b1, acc11, 0, 0, 0);
  }
  #pragma unroll
  for (int j = 0; j < 2; ++j) {
    const int n = n0 + wn + j * 16 + lr;
    const float bias = bih[n] + bhh[n];
    #pragma unroll
    for (int i = 0; i < 2; ++i) {
      const int mb = m0 + wm + i * 16 + quad * 4;
      floatx4 av = (i == 0) ? (j == 0 ? acc00 : acc01) : (j == 0 ? acc10 : acc11);
      #pragma unroll
      for (int rr = 0; rr < 4; ++rr) {
        G[(size_t)(mb + rr) * 2048 + n] = f2bf(av[rr] + bias);
      }
    }
  }
}

// ---------------- LSTM recurrence via MFMA, weights resident in VGPRs ----------------
// v6b: DUAL-STREAM (same design as v6; resubmit with hang-hardening).
// The two directions are independent recurrences; one block (slice,bg) runs
// BOTH, alternating phases so each stream's ~4.5-4.8k-cycle store->LLC->poll
// round trip hides under the other stream's poll+compute. Per 2 steps the loop
// pays ~one exchange latency instead of two. Whh is 1-term fp16 so both dirs
// fit in 256 VGPRs (fp16-W gate error ~1e-4, ~100x below bf16-G quantization).
// h stays bf16 through the exchange (unchanged v3 protocol/tags/layout).
// HARDENING vs v6: spin cap 1<<14 (a broken protocol now finishes in ~1s and
// fails verification visibly instead of timing out the container); Hb is
// explicitly 0xAAAA-poisoned before layer 0.
__launch_bounds__(256, 1)
__global__ void rec_k(const u16* __restrict__ G, const float* __restrict__ whh_l,
                      u32* __restrict__ Hbuf, int tag_base,
                      u16* __restrict__ Xbf, u32* __restrict__ Xu) {
  __shared__ u16 hlds[2][2][16][256];  // [dir][parity][b][k] fp16 bits; rows 8..15 zero
  __shared__ u32 xst[2][8192];         // [dir][16 slots * 512] X staging

  const int tid = threadIdx.x;
  const int slice = blockIdx.x >> 2;
  const int bg = blockIdx.x & 3;
  const int s64 = slice * 64;
  const int w = tid >> 6;       // wave = hidden-16 chunk within slice
  const int lane = tid & 63;
  const int q = lane >> 4;
  const int lr = lane & 15;
  const int bl = lr & 7;        // batch (lanes lr>=8 are update-helpers)
  const int hh = lr >> 3;       // 0: cells rr 0,1   1: cells rr 2,3

  // ---- one-time: Whh rows, all 4 gate types, BOTH dirs, fp16 1-term ----
  half8v Ah[2][4][8];
  #pragma unroll
  for (int d = 0; d < 2; ++d) {
    #pragma unroll
    for (int t = 0; t < 4; ++t) {
      const float* wrow = whh_l + (size_t)d * 262144
                        + (size_t)(t * 256 + s64 + w * 16 + lr) * 256;
      #pragma unroll
      for (int ks = 0; ks < 8; ++ks) {
        const float* pk = wrow + ks * 32 + q * 8;
        half8v hv;
        #pragma unroll
        for (int j = 0; j < 8; ++j) hv[j] = (_Float16)pk[j];
        Ah[d][t][ks] = hv;
      }
    }
  }
  for (int i = tid; i < 2 * 2 * 16 * 256; i += 256) ((u16*)hlds)[i] = 0;
  float cst[2][2] = {{0.f, 0.f}, {0.f, 0.f}};   // c-state per stream

  u32* hbp[2] = { Hbuf + (size_t)bg * 4096, Hbuf + (size_t)(4 + bg) * 4096 };
  const u16* gb[2];
  gb[0] = G + (size_t)(bg * 8 + bl) * 2048 + s64 + w * 16 + q * 4 + hh * 2;
  gb[1] = gb[0] + 1024;

  // preamble: G[st=0] both streams
  u32 gvv[2][4], gnn[2][4];
  #pragma unroll
  for (int d = 0; d < 2; ++d) {
    const int t0 = d ? 511 : 0;
    const u16* gp = gb[d] + (size_t)t0 * 32 * 2048;
    gvv[d][0] = *(const u32*)(gp);
    gvv[d][1] = *(const u32*)(gp + 256);
    gvv[d][2] = *(const u32*)(gp + 512);
    gvv[d][3] = *(const u32*)(gp + 768);
  }

  for (int st = 0; st < 512; ++st) {
    #pragma unroll
    for (int d = 0; d < 2; ++d) {
      if (st > 0) {
        // tagged-data poll (protocol identical to v3/v5)
        const u32 want = (u32)((tag_base + st) & 0xffff);
        const u32* aLL = hbp[d] + (st & 1) * 2048 + tid * 8;
        u32x4 qa, qb;
        int it = 0;
        for (;;) {
          poll8_llc(aLL, qa, qb);
          if (match8(qa, qb, want)) break;
          if (++it > (1 << 14)) break;   // hang-avoidance: fast visible failure
        }
        // bf16 hi -> fp16 bits (exact), pack pairs -> swizzled 16B LDS write
        u16 h0 = f2h(__uint_as_float(qa[0] & 0xffff0000u));
        u16 h1 = f2h(__uint_as_float(qa[1] & 0xffff0000u));
        u16 h2 = f2h(__uint_as_float(qa[2] & 0xffff0000u));
        u16 h3 = f2h(__uint_as_float(qa[3] & 0xffff0000u));
        u16 h4 = f2h(__uint_as_float(qb[0] & 0xffff0000u));
        u16 h5 = f2h(__uint_as_float(qb[1] & 0xffff0000u));
        u16 h6 = f2h(__uint_as_float(qb[2] & 0xffff0000u));
        u16 h7 = f2h(__uint_as_float(qb[3] & 0xffff0000u));
        const int pb = tid >> 5, pc = tid & 31;
        uint4 hv = { (u32)h0 | ((u32)h1 << 16), (u32)h2 | ((u32)h3 << 16),
                     (u32)h4 | ((u32)h5 << 16), (u32)h6 | ((u32)h7 << 16) };
        *(uint4*)&hlds[d][st & 1][pb][(pc ^ pb) * 8] = hv;
      }
      __syncthreads();   // one barrier per stream phase
      if (d == 0) {
        // early-issue NEXT step's G (both streams): its HBM latency drains
        // inside phase-1's poll wait (which is waiting on tags anyway)
        {
          const int stn = (st < 511) ? st + 1 : 511;
          #pragma unroll
          for (int dd = 0; dd < 2; ++dd) {
            const int tn = dd ? (511 - stn) : stn;
            const u16* gp = gb[dd] + (size_t)tn * 32 * 2048;
            gnn[dd][0] = *(const u32*)(gp);
            gnn[dd][1] = *(const u32*)(gp + 256);
            gnn[dd][2] = *(const u32*)(gp + 512);
            gnn[dd][3] = *(const u32*)(gp + 768);
          }
        }
        // batched X dump for previous 8 steps, both streams (barrier-ordered)
        if ((st & 7) == 0 && st > 0) {
          const int st0 = st - 8;
          if (Xbf) {
            #pragma unroll
            for (int dd = 0; dd < 2; ++dd) {
              #pragma unroll
              for (int half = 0; half < 2; ++half) {
                const int seg = half * 256 + tid;
                const int slot = seg >> 6, r = seg & 63;
                const int b = r >> 3, f8 = (r & 7) * 8;
                const int sl = (st0 + slot) & 15;
                const int ofs = sl * 512 + b * 64 + f8;          // u16 units
                const int sw = ((ofs >> 3) ^ b) << 3;
                uint4 vv = *(const uint4*)((const u16*)&xst[dd][0] + sw);
                const int tt = dd ? (511 - (st0 + slot)) : (st0 + slot);
                *(uint4*)(Xbf + ((size_t)tt * 32 + bg * 8 + b) * 512
                          + dd * 256 + s64 + f8) = vv;
              }
            }
          } else {
            #pragma unroll
            for (int dd = 0; dd < 2; ++dd) {
              #pragma unroll
              for (int half = 0; half < 4; ++half) {
                const int seg = half * 256 + tid;
                const int slot = seg >> 7, rem = seg & 127;
                const int b = rem >> 4, f4 = (rem & 15) * 4;
                const int sl = (st0 + slot) & 15;
                const int ofs = sl * 512 + b * 64 + f4;          // u32 units
                const int sw = ((ofs >> 2) ^ b) << 2;
                uint4 vv = *(const uint4*)((const u32*)&xst[dd][0] + sw);
                const int tt = dd ? (511 - (st0 + slot)) : (st0 + slot);
                *(uint4*)(Xu + ((size_t)tt * 32 + bg * 8 + b) * 512
                          + dd * 256 + s64 + f4) = vv;
              }
            }
          }
        }
      }
      // MFMA: acc[t][rr] = gate t of cell (hl=w*16+q*4+rr, b=lr); fp16 1-term
      floatx4 a0 = {0,0,0,0}, a1 = {0,0,0,0}, a2 = {0,0,0,0}, a3 = {0,0,0,0};
      const u16* hrow = &hlds[d][st & 1][lr][0];
      #pragma unroll
      for (int ks = 0; ks < 8; ++ks) {
        half8v bh = *(const half8v*)&hrow[((ks * 4 + q) ^ bl) * 8];
        a0 = __builtin_amdgcn_mfma_f32_16x16x32_f16(Ah[d][0][ks], bh, a0, 0, 0, 0);
        a1 = __builtin_amdgcn_mfma_f32_16x16x32_f16(Ah[d][1][ks], bh, a1, 0, 0, 0);
        a2 = __builtin_amdgcn_mfma_f32_16x16x32_f16(Ah[d][2][ks], bh, a2, 0, 0, 0);
        a3 = __builtin_amdgcn_mfma_f32_16x16x32_f16(Ah[d][3][ks], bh, a3, 0, 0, 0);
      }
      // ship cells rr=2,3 to the helper half-wave
      float sh0a = __shfl_xor(a0[2], 8, 64), sh0b = __shfl_xor(a0[3], 8, 64);
      float sh1a = __shfl_xor(a1[2], 8, 64), sh1b = __shfl_xor(a1[3], 8, 64);
      float sh2a = __shfl_xor(a2[2], 8, 64), sh2b = __shfl_xor(a2[3], 8, 64);
      float sh3a = __shfl_xor(a3[2], 8, 64), sh3b = __shfl_xor(a3[3], 8, 64);
      // in-register LSTM cell update: 2 cells per lane
      const u32 wtag = (u32)((tag_base + st + 1) & 0xffff);
      float hf0, hf1; u32 hw0, hw1;
      {
        float mi = hh ? sh0a : a0[0];
        float mf = hh ? sh1a : a1[0];
        float mg = hh ? sh2a : a2[0];
        float mo = hh ? sh3a : a3[0];
        float si = bf2f((u16)(gvv[d][0])) + mi;
        float sf = bf2f((u16)(gvv[d][1])) + mf;
        float sg = bf2f((u16)(gvv[d][2])) + mg;
        float so = bf2f((u16)(gvv[d][3])) + mo;
        float ig = sigf(si), fg = sigf(sf), gg = tanh_f(sg), og = sigf(so);
        float cn = fg * cst[d][0] + ig * gg;
        hf0 = og * tanh_f(cn);
        cst[d][0] = cn;
        hw0 = ((u32)f2bf(hf0) << 16) | wtag;
      }
      {
        float mi = hh ? sh0b : a0[1];
        float mf = hh ? sh1b : a1[1];
        float mg = hh ? sh2b : a2[1];
        float mo = hh ? sh3b : a3[1];
        float si = bf2f((u16)(gvv[d][0] >> 16)) + mi;
        float sf = bf2f((u16)(gvv[d][1] >> 16)) + mf;
        float sg = bf2f((u16)(gvv[d][2] >> 16)) + mg;
        float so = bf2f((u16)(gvv[d][3] >> 16)) + mo;
        float ig = sigf(si), fg = sigf(sf), gg = tanh_f(sg), og = sigf(so);
        float cn = fg * cst[d][1] + ig * gg;
        hf1 = og * tanh_f(cn);
        cst[d][1] = cn;
        hw1 = ((u32)f2bf(hf1) << 16) | wtag;
      }
      // fire-and-forget tagged h store (one 8B store/lane, full-line-forming)
      {
        const int hoff = ((st + 1) & 1) * 2048 + bl * 256 + s64
                       + w * 16 + q * 4 + hh * 2;
        store8_cc(hbp[d] + hoff, (u64)hw0 | ((u64)hw1 << 32));
      }
      // stage X in LDS (swizzled; dumped every 8 steps)
      if (Xbf) {
        const int ofs = (st & 15) * 512 + bl * 64 + w * 16 + q * 4 + hh * 2; // u16
        const int sw = (((ofs >> 3) ^ bl) << 3) | (ofs & 7);
        *(u32*)((u16*)&xst[d][0] + sw) = (hw0 >> 16) | ((hw1 >> 16) << 16);
      } else {
        const int ofs = (st & 15) * 512 + bl * 64 + w * 16 + q * 4 + hh * 2; // u32
        const int sw = (((ofs >> 2) ^ bl) << 2) | (ofs & 3);
        u16 g0 = (u16)(hw0 >> 16), g1 = (u16)(hw1 >> 16);
        u32 x0 = ((u32)g0 << 16) | f2bf(hf0 - bf2f(g0));
        u32 x1 = ((u32)g1 << 16) | f2bf(hf1 - bf2f(g1));
        *(u64*)((u32*)&xst[d][0] + sw) = (u64)x0 | ((u64)x1 << 32);
      }
    } // stream d
    // rotate prefetched G into place (both streams consumed theirs above)
    #pragma unroll
    for (int d = 0; d < 2; ++d) {
      gvv[d][0] = gnn[d][0]; gvv[d][1] = gnn[d][1];
      gvv[d][2] = gnn[d][2]; gvv[d][3] = gnn[d][3];
    }
    // NO end-of-step barrier, NO store drain, NO flag.
  }
  // epilogue: dump last 8 staged steps, both streams
  __syncthreads();
  {
    const int st0 = 504;
    if (Xbf) {
      #pragma unroll
      for (int dd = 0; dd < 2; ++dd) {
        #pragma unroll
        for (int half = 0; half < 2; ++half) {
          const int seg = half * 256 + tid;
          const int slot = seg >> 6, r = seg & 63;
          const int b = r >> 3, f8 = (r & 7) * 8;
          const int sl = (st0 + slot) & 15;
          const int ofs = sl * 512 + b * 64 + f8;
          const int sw = ((ofs >> 3) ^ b) << 3;
          uint4 vv = *(const uint4*)((const u16*)&xst[dd][0] + sw);
          const int tt = dd ? (511 - (st0 + slot)) : (st0 + slot);
          *(uint4*)(Xbf + ((size_t)tt * 32 + bg * 8 + b) * 512
                    + dd * 256 + s64 + f8) = vv;
        }
      }
    } else {
      #pragma unroll
      for (int dd = 0; dd < 2; ++dd) {
        #pragma unroll
        for (int half = 0; half < 4; ++half) {
          const int seg = half * 256 + tid;
          const int slot = seg >> 7, rem = seg & 127;
          const int b = rem >> 4, f4 = (rem & 15) * 4;
          const int sl = (st0 + slot) & 15;
          const int ofs = sl * 512 + b * 64 + f4;
          const int sw = ((ofs >> 2) ^ b) << 2;
          uint4 vv = *(const uint4*)((const u32*)&xst[dd][0] + sw);
          const int tt = dd ? (511 - (st0 + slot)) : (st0 + slot);
          *(uint4*)(Xu + ((size_t)tt * 32 + bg * 8 + b) * 512
                    + dd * 256 + s64 + f4) = vv;
        }
      }
    }
  }
}

// ---------------- LayerNorm + classifier head; logits -> d_out+1 ----------------
// X2u: packed (bf16hi<<16|bf16lo) per element; decode = bf2f(hi)+bf2f(lo)
__global__ void head_k(const u32* __restrict__ X2u, const float* __restrict__ gamma,
                       const float* __restrict__ beta, const float* __restrict__ cw,
                       const float* __restrict__ cb, float* __restrict__ out) {
  __shared__ float red[9][64];
  const int m = blockIdx.x, lane = threadIdx.x;
  const int s = m >> 5, b = m & 31;
  const uint4* xp = (const uint4*)(X2u + (size_t)m * 512) + lane * 2;
  uint4 a0 = xp[0], a1 = xp[1];
  float x[8];
  x[0] = decode_hl(a0.x); x[1] = decode_hl(a0.y);
  x[2] = decode_hl(a0.z); x[3] = decode_hl(a0.w);
  x[4] = decode_hl(a1.x); x[5] = decode_hl(a1.y);
  x[6] = decode_hl(a1.z); x[7] = decode_hl(a1.w);
  float sm = 0.f, sq = 0.f;
  #pragma unroll
  for (int i = 0; i < 8; ++i) { sm += x[i]; sq += x[i] * x[i]; }
  #pragma unroll
  for (int off = 32; off > 0; off >>= 1) {
    sm += __shfl_xor(sm, off, 64);
    sq += __shfl_xor(sq, off, 64);
  }
  const float mu = sm * (1.0f / 512.0f);
  const float var = sq * (1.0f / 512.0f) - mu * mu;
  const float rs = rsqrtf(var + 1e-5f);
  const float4* gp = (const float4*)gamma + lane * 2;
  const float4* bp = (const float4*)beta + lane * 2;
  float4 g0 = gp[0], g1 = gp[1], be0 = bp[0], be1 = bp[1];
  float nv[8];
  nv[0] = (x[0] - mu) * rs * g0.x + be0.x;
  nv[1] = (x[1] - mu) * rs * g0.y + be0.y;
  nv[2] = (x[2] - mu) * rs * g0.z + be0.z;
  nv[3] = (x[3] - mu) * rs * g0.w + be0.w;
  nv[4] = (x[4] - mu) * rs * g1.x + be1.x;
  nv[5] = (x[5] - mu) * rs * g1.y + be1.y;
  nv[6] = (x[6] - mu) * rs * g1.z + be1.z;
  nv[7] = (x[7] - mu) * rs * g1.w + be1.w;
  #pragma unroll
  for (int c = 0; c < 9; ++c) {
    const float4* wp = (const float4*)(cw + (size_t)c * 512) + lane * 2;
    float4 w0 = wp[0], w1 = wp[1];
    red[c][lane] = nv[0]*w0.x + nv[1]*w0.y + nv[2]*w0.z + nv[3]*w0.w
                 + nv[4]*w1.x + nv[5]*w1.y + nv[6]*w1.z + nv[7]*w1.w;
  }
  __syncthreads();
  if (lane < 9) {
    float t = 0.f;
    for (int i = 0; i < 64; ++i) t += red[lane][i];
    out[1 + ((size_t)b * 512 + s) * 9 + lane] = t + cb[lane];
  }
}

// ---------------- CRF NLL: one wave per batch element ----------------
__global__ void crf_k(const float* __restrict__ logits, const int* __restrict__ labels,
                      const int* __restrict__ lens, const float* __restrict__ tr,
                      float* __restrict__ loss) {
  const int b = blockIdx.x, lane = threadIdx.x;
  const int len = lens[b];
  float trj[9];
  #pragma unroll
  for (int i = 0; i < 9; ++i) trj[i] = 0.f;
  if (lane < 9) {
    #pragma unroll
    for (int i = 0; i < 9; ++i) trj[i] = tr[i * 11 + lane];
  }
  float alpha = -1e30f;
  if (lane < 9) alpha = tr[9 * 11 + lane] + logits[(size_t)b * 512 * 9 + lane];
  for (int t = 1; t < len; ++t) {
    float e = (lane < 9) ? logits[((size_t)b * 512 + t) * 9 + lane] : 0.f;
    float v[9];
    float mx = -1e30f;
    #pragma unroll
    for (int i = 0; i < 9; ++i) {
      v[i] = __shfl(alpha, i, 64) + trj[i];
      mx = fmaxf(mx, v[i]);
    }
    float ss = 0.f;
    #pragma unroll
    for (int i = 0; i < 9; ++i) ss += __expf(v[i] - mx);
    float na = mx + __logf(ss) + e;
    if (lane < 9) alpha = na;
  }
  float fin = (lane < 9) ? alpha + tr[lane * 11 + 10] : -1e30f;
  float mx = fin;
  #pragma unroll
  for (int off = 8; off > 0; off >>= 1) mx = fmaxf(mx, __shfl_xor(mx, off, 64));
  float es = (lane < 9) ? __expf(fin - mx) : 0.f;
  #pragma unroll
  for (int off = 8; off > 0; off >>= 1) es += __shfl_xor(es, off, 64);
  const float logZ = mx + __logf(es);
  float emit = 0.f, ts = 0.f;
  for (int t = lane; t < len; t += 64) {
    int y = labels[b * 512 + t];
    emit += logits[((size_t)b * 512 + t) * 9 + y];
  }
  for (int t = 1 + lane; t < len; t += 64) {
    int y0 = labels[b * 512 + t - 1], y1 = labels[b * 512 + t];
    ts += tr[y0 * 11 + y1];
  }
  #pragma unroll
  for (int off = 32; off > 0; off >>= 1) {
    emit += __shfl_xor(emit, off, 64);
    ts += __shfl_xor(ts, off, 64);
  }
  if (lane == 0) {
    int y0 = labels[b * 512], yl = labels[b * 512 + len - 1];
    float gold = emit + ts + tr[9 * 11 + y0] + tr[yl * 11 + 10];
    atomicAdd(loss, (logZ - gold) * (1.0f / 32.0f));
  }
}

extern "C" void kernel_launch(void* const* d_in, const int* in_sizes, int n_in,
                              void* d_out, int out_size, void* d_ws, size_t ws_size,
                              hipStream_t stream) {
  const int* ids = (const int*)d_in[0];
  const int* amask = (const int*)d_in[1];
  const int* lens = (const int*)d_in[2];
  const int* labels = (const int*)d_in[3];
  const float* emb = (const float*)d_in[4];
  const float* w_ih = (const float*)d_in[5];
  const float* w_hh = (const float*)d_in[6];
  const float* b_ih = (const float*)d_in[7];
  const float* b_hh = (const float*)d_in[8];
  const float* gamma = (const float*)d_in[9];
  const float* beta = (const float*)d_in[10];
  const float* cw = (const float*)d_in[11];
  const float* cb = (const float*)d_in[12];
  const float* tr = (const float*)d_in[13];
  (void)in_sizes; (void)n_in; (void)out_size;

  if (ws_size < WS_NEEDED) return;  // workspace too small -> clean failure

  char* p = (char*)d_ws;
  u16* X0 = (u16*)p;      p += (size_t)16384 * 512 * 2;        // 16.78 MB
  u16* Wbf = (u16*)p;     p += (size_t)2 * 2 * 1024 * 512 * 2; // 4.19 MB
  u16* G = (u16*)p;       p += (size_t)16384 * 2048 * 2;       // 67.1 MB
  u16* X1 = (u16*)p;      p += (size_t)16384 * 512 * 2;        // 16.78 MB
  u32* X2u = (u32*)p;     p += (size_t)16384 * 512 * 4;        // 33.55 MB
  u32* Hb = (u32*)p;      p += (size_t)32768 * 4;              // 128 KB (LLC exchange)
  float* out = (float*)d_out;

  prep_k<<<16384, 64, 0, stream>>>(ids, amask, emb, X0);
  conv_k<<<1024, 256, 0, stream>>>(w_ih, Wbf, 262144);
  zero_k<<<1, 64, 0, stream>>>(out);
  poison_k<<<32, 256, 0, stream>>>(Hb);   // explicit 0xAAAA: tags never alias
  // Layer 0 (tags 1..512)
  gemm_k<<<dim3(256, 32), 256, 0, stream>>>(X0, Wbf, b_ih, b_hh, G);
  rec_k<<<16, 256, 0, stream>>>(G, w_hh, Hb, 0, X1, nullptr);
  // Layer 1 (tags 1025..1536 — never aliases layer 0 or 0xAAAA poison)
  gemm_k<<<dim3(256, 32), 256, 0, stream>>>(X1, Wbf + 2 * 1024 * 512,
                                            b_ih + 2048, b_hh + 2048, G);
  rec_k<<<16, 256, 0, stream>>>(G, w_hh + 2 * 1024 * 256, Hb, 1024,
                                nullptr, X2u);
  // Head + CRF
  head_k<<<16384, 64, 0, stream>>>(X2u, gamma, beta, cw, cb, out);
  crf_k<<<32, 64, 0, stream>>>(out + 1, labels, lens, tr, out);
}

// Round 7
// 2663.904 us; speedup vs baseline: 1.5339x; 1.5339x over previous
//
#include <hip/hip_runtime.h>

// Problem dims
#define B_ 32
#define S_ 512
#define D_ 512
#define H_ 256

typedef float floatx4 __attribute__((ext_vector_type(4)));
typedef short short8v __attribute__((ext_vector_type(8)));
typedef _Float16 half8v __attribute__((ext_vector_type(8)));
typedef unsigned short u16;
typedef unsigned int u32;
typedef unsigned long long u64;
typedef u32 u32x4 __attribute__((ext_vector_type(4)));

#define WS_NEEDED 138575872ull

__device__ __forceinline__ u16 f2bf(float f) {
  u32 x = __float_as_uint(f);
  x += 0x7fffu + ((x >> 16) & 1u);   // RNE
  return (u16)(x >> 16);
}
__device__ __forceinline__ float bf2f(u16 h) {
  return __uint_as_float(((u32)h) << 16);
}
__device__ __forceinline__ float decode_hl(u32 v) {
  return bf2f((u16)(v >> 16)) + bf2f((u16)(v & 0xffffu));
}
__device__ __forceinline__ u16 f2h(float f) {     // f32 -> fp16 bits (RNE)
  union { _Float16 h; u16 u; } cv; cv.h = (_Float16)f; return cv.u;
}
__device__ __forceinline__ float sigf(float x) {
  return 1.0f / (1.0f + __expf(-x));
}
__device__ __forceinline__ float tanh_f(float x) {
  float e = __expf(-2.0f * fabsf(x));
  float r = (1.0f - e) / (1.0f + e);
  return copysignf(r, x);
}
// LLC-visible 8B store (v3-proven: full-line-forming across the wave).
__device__ __forceinline__ void store8_cc(u32* p, u64 v) {
  asm volatile("global_store_dwordx2 %0, %1, off sc0 sc1"
               :: "v"(p), "v"(v) : "memory");
}
// 4B subset poll, LLC-served: ~half the per-iteration latency of the 32B poll.
__device__ __forceinline__ u32 poll1_llc(const u32* p) {
  u32 v;
  asm volatile("global_load_dword %0, %1, off sc0 sc1\n\t"
               "s_waitcnt vmcnt(0)"
               : "=v"(v) : "v"(p) : "memory");
  return v;
}
// 32B verify read, LLC-served (sc0 sc1 — v3/v5-proven visibility class).
__device__ __forceinline__ void poll8_llc(const u32* p, u32x4& a, u32x4& b) {
  asm volatile("global_load_dwordx4 %0, %2, off sc0 sc1\n\t"
               "global_load_dwordx4 %1, %2, off offset:16 sc0 sc1\n\t"
               "s_waitcnt vmcnt(0)"
               : "=&v"(a), "=&v"(b) : "v"(p) : "memory");
}
__device__ __forceinline__ bool match8(u32x4 a, u32x4 b, u32 want) {
  return ((a[0] & 0xffffu) == want) && ((a[1] & 0xffffu) == want)
      && ((a[2] & 0xffffu) == want) && ((a[3] & 0xffffu) == want)
      && ((b[0] & 0xffffu) == want) && ((b[1] & 0xffffu) == want)
      && ((b[2] & 0xffffu) == want) && ((b[3] & 0xffffu) == want);
}

struct alignas(16) U16x8 { u16 v[8]; };

// ---------------- embedding -> X0 bf16, time-major (m = s*32+b, 512 feats) ----------------
__global__ void prep_k(const int* __restrict__ ids, const int* __restrict__ amask,
                       const float* __restrict__ emb, u16* __restrict__ X0) {
  int m = blockIdx.x;            // m = s*32 + b
  int lane = threadIdx.x;        // 64
  int s = m >> 5, b = m & 31;
  int id = ids[b * S_ + s];
  int mk = amask[b * S_ + s];
  const float4* src = (const float4*)(emb + (size_t)id * D_) + lane * 2;
  float4 v0 = src[0], v1 = src[1];
  if (!mk) { v0 = make_float4(0,0,0,0); v1 = make_float4(0,0,0,0); }
  U16x8 o;
  o.v[0]=f2bf(v0.x); o.v[1]=f2bf(v0.y); o.v[2]=f2bf(v0.z); o.v[3]=f2bf(v0.w);
  o.v[4]=f2bf(v1.x); o.v[5]=f2bf(v1.y); o.v[6]=f2bf(v1.z); o.v[7]=f2bf(v1.w);
  *(U16x8*)(X0 + (size_t)m * D_ + lane * 8) = o;
}

// ---------------- fp32 -> bf16 weight convert (w_ih, 2*2*1024*512 elems) ----------------
__global__ void conv_k(const float* __restrict__ w, u16* __restrict__ wbf, int n8) {
  int idx = blockIdx.x * blockDim.x + threadIdx.x;
  if (idx >= n8) return;
  const float4* s = (const float4*)w + (size_t)idx * 2;
  float4 v0 = s[0], v1 = s[1];
  U16x8 o;
  o.v[0]=f2bf(v0.x); o.v[1]=f2bf(v0.y); o.v[2]=f2bf(v0.z); o.v[3]=f2bf(v0.w);
  o.v[4]=f2bf(v1.x); o.v[5]=f2bf(v1.y); o.v[6]=f2bf(v1.z); o.v[7]=f2bf(v1.w);
  *(U16x8*)(wbf + (size_t)idx * 8) = o;
}

// ---------------- zero loss ----------------
__global__ void zero_k(float* __restrict__ loss) {
  if (threadIdx.x == 0) *loss = 0.f;
}

// ---------------- poison the exchange replicas (tags can never match 0xAAAA) ----------------
__global__ void poison_k(u32* __restrict__ p) {
  const int i = (blockIdx.x * blockDim.x + threadIdx.x) * 4;
  uint4 v = make_uint4(0xAAAAAAAAu, 0xAAAAAAAAu, 0xAAAAAAAAu, 0xAAAAAAAAu);
  *(uint4*)(p + i) = v;
}

// ---------------- bf16 MFMA GEMM: G[m][n] = A[m][:] . W[n][:] + bih[n] + bhh[n] ----------------
__global__ void gemm_k(const u16* __restrict__ A, const u16* __restrict__ W,
                       const float* __restrict__ bih, const float* __restrict__ bhh,
                       u16* __restrict__ G) {
  __shared__ short Asm[64 * 40];
  __shared__ short Bsm[64 * 40];
  const int tid = threadIdx.x;
  const int m0 = blockIdx.x * 64, n0 = blockIdx.y * 64;
  const int wid = tid >> 6, lane = tid & 63;
  const int quad = lane >> 4, lr = lane & 15;
  const int wm = (wid >> 1) * 32, wn = (wid & 1) * 32;
  const int lrow = tid >> 2, lk = (tid & 3) * 8;
  floatx4 acc00 = {0,0,0,0}, acc01 = {0,0,0,0}, acc10 = {0,0,0,0}, acc11 = {0,0,0,0};
  for (int kt = 0; kt < 16; ++kt) {
    const int k0 = kt * 32;
    uint4 av = *(const uint4*)(A + (size_t)(m0 + lrow) * 512 + k0 + lk);
    uint4 bv = *(const uint4*)(W + (size_t)(n0 + lrow) * 512 + k0 + lk);
    __syncthreads();
    *(uint4*)&Asm[lrow * 40 + lk] = av;
    *(uint4*)&Bsm[lrow * 40 + lk] = bv;
    __syncthreads();
    short8v a0 = *(const short8v*)&Asm[(wm + lr) * 40 + quad * 8];
    short8v a1 = *(const short8v*)&Asm[(wm + 16 + lr) * 40 + quad * 8];
    short8v b0 = *(const short8v*)&Bsm[(wn + lr) * 40 + quad * 8];
    short8v b1 = *(const short8v*)&Bsm[(wn + 16 + lr) * 40 + quad * 8];
    acc00 = __builtin_amdgcn_mfma_f32_16x16x32_bf16(a0, b0, acc00, 0, 0, 0);
    acc01 = __builtin_amdgcn_mfma_f32_16x16x32_bf16(a0, b1, acc01, 0, 0, 0);
    acc10 = __builtin_amdgcn_mfma_f32_16x16x32_bf16(a1, b0, acc10, 0, 0, 0);
    acc11 = __builtin_amdgcn_mfma_f32_16x16x32_bf16(a1, b1, acc11, 0, 0, 0);
  }
  #pragma unroll
  for (int j = 0; j < 2; ++j) {
    const int n = n0 + wn + j * 16 + lr;
    const float bias = bih[n] + bhh[n];
    #pragma unroll
    for (int i = 0; i < 2; ++i) {
      const int mb = m0 + wm + i * 16 + quad * 4;
      floatx4 av = (i == 0) ? (j == 0 ? acc00 : acc01) : (j == 0 ? acc10 : acc11);
      #pragma unroll
      for (int rr = 0; rr < 4; ++rr) {
        G[(size_t)(mb + rr) * 2048 + n] = f2bf(av[rr] + bias);
      }
    }
  }
}

// ---------------- LSTM recurrence via MFMA, weights resident in VGPRs ----------------
// v7 = v3 skeleton (single stream, 32 blocks, 1 barrier/step) + v6b's fp16
// 1-term Whh (proven absmax) + exchange-protocol latency attack:
//  (1) PRIVATE REPLICAS: producer stores its tagged h to FOUR replica regions
//      (4x full-line 8B stores, fire-and-forget). Each consumer polls its OWN
//      replica -> no hot-line sharing among the 4 consumer blocks of a group
//      (was: 4 blocks x 256 threads hammering the same 8KB of LLC lines).
//  (2) SUBSET POLL: spin on ONE dword (~450cy/iter vs ~1000cy for 32B), then
//      one 32B verify read. The thread's 32B comes from a single producer
//      wave-instruction, so subset-arrival implies full-arrival almost always;
//      the verify loop catches stragglers. Tags still cover every u32.
// Everything else (tags, parity, LDS layout, X staging, G prefetch) = v3.
__launch_bounds__(256, 1)
__global__ void rec_k(const u16* __restrict__ G, const float* __restrict__ whh_l,
                      u32* __restrict__ Hb4, int tag_base,
                      u16* __restrict__ Xbf, u32* __restrict__ Xu) {
  __shared__ u16 hlds[2][16][256];   // [parity][b][k] fp16 bits; rows 8..15 stay zero
  __shared__ u32 xst[16 * 512];      // X staging, 16 slots (u16 view for layer0)

  const int tid = threadIdx.x;
  const int slice = blockIdx.x >> 3;
  const int dir = (blockIdx.x >> 2) & 1;
  const int bg = blockIdx.x & 3;
  const int s64 = slice * 64;
  const int w = tid >> 6;       // wave = hidden-16 chunk within slice
  const int lane = tid & 63;
  const int q = lane >> 4;
  const int lr = lane & 15;
  const int bl = lr & 7;        // batch (lanes lr>=8 are update-helpers)
  const int hh = lr >> 3;       // 0: cells rr 0,1   1: cells rr 2,3

  const float* whh = whh_l + (size_t)dir * (1024 * 256);

  // ---- one-time: Whh rows for all 4 gate types of hidden chunk, fp16 1-term ----
  half8v Ah[4][8];
  #pragma unroll
  for (int t = 0; t < 4; ++t) {
    const float* wrow = whh + (size_t)(t * 256 + s64 + w * 16 + lr) * 256;
    #pragma unroll
    for (int ks = 0; ks < 8; ++ks) {
      const float* pk = wrow + ks * 32 + q * 8;
      half8v hv;
      #pragma unroll
      for (int j = 0; j < 8; ++j) hv[j] = (_Float16)pk[j];
      Ah[t][ks] = hv;
    }
  }
  for (int i = tid; i < 2 * 16 * 256; i += 256) ((u16*)hlds)[i] = 0;
  float cst[2] = {0.f, 0.f};    // c-state (batch bl, cells rr=hh*2, hh*2+1)

  // replica layout: Hb4[grp][replica][parity][2048]; grp = dir*4+bg
  u32* hbg = Hb4 + (size_t)(dir * 4 + bg) * 16384;
  u32* myrep = hbg + (size_t)slice * 4096;     // consumer's private replica
  // G for this lane: 4 types x 2 cells (rr = hh*2, hh*2+1), batch bl
  const u16* gbase = G + (size_t)(bg * 8 + bl) * 2048 + dir * 1024
                   + s64 + w * 16 + q * 4 + hh * 2;

  // preamble: load G[st=0]
  u32 gv0, gv1, gv2, gv3;
  {
    const int t0 = dir ? 511 : 0;
    const u16* gp = gbase + (size_t)t0 * 32 * 2048;
    gv0 = *(const u32*)(gp);
    gv1 = *(const u32*)(gp + 256);
    gv2 = *(const u32*)(gp + 512);
    gv3 = *(const u32*)(gp + 768);
  }

  for (int st = 0; st < 512; ++st) {
    if (st > 0) {
      // tagged-data poll on the PRIVATE replica: subset dword spin + 32B verify
      const u32 want = (u32)((tag_base + st) & 0xffff);
      const u32* ap = myrep + (st & 1) * 2048 + tid * 8;
      int it = 0;
      for (;;) {
        u32 s0 = poll1_llc(ap);
        if ((s0 & 0xffffu) == want) break;
        if (++it > (1 << 14)) break;   // hang-avoidance: fast visible failure
      }
      u32x4 qa, qb;
      int it2 = 0;
      for (;;) {
        poll8_llc(ap, qa, qb);
        if (match8(qa, qb, want)) break;
        if (++it2 > (1 << 12)) break;  // hang-avoidance only
      }
      // bf16 hi -> fp16 bits (exact), pack pairs -> swizzled 16B LDS write
      u16 h0 = f2h(__uint_as_float(qa[0] & 0xffff0000u));
      u16 h1 = f2h(__uint_as_float(qa[1] & 0xffff0000u));
      u16 h2 = f2h(__uint_as_float(qa[2] & 0xffff0000u));
      u16 h3 = f2h(__uint_as_float(qa[3] & 0xffff0000u));
      u16 h4 = f2h(__uint_as_float(qb[0] & 0xffff0000u));
      u16 h5 = f2h(__uint_as_float(qb[1] & 0xffff0000u));
      u16 h6 = f2h(__uint_as_float(qb[2] & 0xffff0000u));
      u16 h7 = f2h(__uint_as_float(qb[3] & 0xffff0000u));
      const int pb = tid >> 5, pc = tid & 31;
      uint4 hv = { (u32)h0 | ((u32)h1 << 16), (u32)h2 | ((u32)h3 << 16),
                   (u32)h4 | ((u32)h5 << 16), (u32)h6 | ((u32)h7 << 16) };
      *(uint4*)&hlds[st & 1][pb][(pc ^ pb) * 8] = hv;
    }
    __syncthreads();   // the ONLY per-step barrier
    // MFMA: acc[t][rr] = gate t of cell (hl=w*16+q*4+rr, b=lr); fp16 1-term
    floatx4 a0 = {0,0,0,0}, a1 = {0,0,0,0}, a2 = {0,0,0,0}, a3 = {0,0,0,0};
    const u16* hrow = &hlds[st & 1][lr][0];
    #pragma unroll
    for (int ks = 0; ks < 8; ++ks) {
      half8v bh = *(const half8v*)&hrow[((ks * 4 + q) ^ bl) * 8];
      a0 = __builtin_amdgcn_mfma_f32_16x16x32_f16(Ah[0][ks], bh, a0, 0, 0, 0);
      a1 = __builtin_amdgcn_mfma_f32_16x16x32_f16(Ah[1][ks], bh, a1, 0, 0, 0);
      a2 = __builtin_amdgcn_mfma_f32_16x16x32_f16(Ah[2][ks], bh, a2, 0, 0, 0);
      a3 = __builtin_amdgcn_mfma_f32_16x16x32_f16(Ah[3][ks], bh, a3, 0, 0, 0);
    }
    // ship cells rr=2,3 to the helper half-wave (their own acc cols are the
    // zero batches). All lanes execute the shuffles; hh=1 lanes use them.
    float sh0a = __shfl_xor(a0[2], 8, 64), sh0b = __shfl_xor(a0[3], 8, 64);
    float sh1a = __shfl_xor(a1[2], 8, 64), sh1b = __shfl_xor(a1[3], 8, 64);
    float sh2a = __shfl_xor(a2[2], 8, 64), sh2b = __shfl_xor(a2[3], 8, 64);
    float sh3a = __shfl_xor(a3[2], 8, 64), sh3b = __shfl_xor(a3[3], 8, 64);
    // in-register LSTM cell update: 2 cells per lane
    const u32 wtag = (u32)((tag_base + st + 1) & 0xffff);
    float hf0, hf1; u32 hw0, hw1;
    {
      float mi = hh ? sh0a : a0[0];
      float mf = hh ? sh1a : a1[0];
      float mg = hh ? sh2a : a2[0];
      float mo = hh ? sh3a : a3[0];
      float si = bf2f((u16)(gv0)) + mi;
      float sf = bf2f((u16)(gv1)) + mf;
      float sg = bf2f((u16)(gv2)) + mg;
      float so = bf2f((u16)(gv3)) + mo;
      float ig = sigf(si), fg = sigf(sf), gg = tanh_f(sg), og = sigf(so);
      float cn = fg * cst[0] + ig * gg;
      hf0 = og * tanh_f(cn);
      cst[0] = cn;
      hw0 = ((u32)f2bf(hf0) << 16) | wtag;
    }
    {
      float mi = hh ? sh0b : a0[1];
      float mf = hh ? sh1b : a1[1];
      float mg = hh ? sh2b : a2[1];
      float mo = hh ? sh3b : a3[1];
      float si = bf2f((u16)(gv0 >> 16)) + mi;
      float sf = bf2f((u16)(gv1 >> 16)) + mf;
      float sg = bf2f((u16)(gv2 >> 16)) + mg;
      float so = bf2f((u16)(gv3 >> 16)) + mo;
      float ig = sigf(si), fg = sigf(sf), gg = tanh_f(sg), og = sigf(so);
      float cn = fg * cst[1] + ig * gg;
      hf1 = og * tanh_f(cn);
      cst[1] = cn;
      hw1 = ((u32)f2bf(hf1) << 16) | wtag;
    }
    // fire-and-forget tagged h store to ALL FOUR replicas (each one 8B
    // store/lane, all 64 lanes -> full-line writes; no drain, no flag)
    {
      const int hoff = ((st + 1) & 1) * 2048 + bl * 256 + s64 + w * 16 + q * 4 + hh * 2;
      const u64 pk = (u64)hw0 | ((u64)hw1 << 32);
      store8_cc(hbg + hoff, pk);
      store8_cc(hbg + 4096 + hoff, pk);
      store8_cc(hbg + 8192 + hoff, pk);
      store8_cc(hbg + 12288 + hoff, pk);
    }
    // stage X in LDS (swizzled; dumped every 8 steps, off the signal path)
    if (Xbf) {
      const int ofs = (st & 15) * 512 + bl * 64 + w * 16 + q * 4 + hh * 2; // u16 units
      const int sw = (((ofs >> 3) ^ bl) << 3) | (ofs & 7);
      *(u32*)((u16*)xst + sw) = (hw0 >> 16) | ((hw1 >> 16) << 16);
    } else {
      const int ofs = (st & 15) * 512 + bl * 64 + w * 16 + q * 4 + hh * 2; // u32 units
      const int sw = (((ofs >> 2) ^ bl) << 2) | (ofs & 3);
      u16 g0 = (u16)(hw0 >> 16), g1 = (u16)(hw1 >> 16);
      u32 x0 = ((u32)g0 << 16) | f2bf(hf0 - bf2f(g0));
      u32 x1 = ((u32)g1 << 16) | f2bf(hf1 - bf2f(g1));
      *(u64*)(xst + sw) = (u64)x0 | ((u64)x1 << 32);
    }
    // batched X dump for previous 8 steps — in the dead window while the
    // h-store propagates. Barrier-ordered vs writers; never touches slot st&15.
    if ((st & 7) == 0 && st > 0) {
      const int st0 = st - 8;
      if (Xbf) {
        #pragma unroll
        for (int half = 0; half < 2; ++half) {
          const int seg = half * 256 + tid;     // 0..511 segs of 16B
          const int slot = seg >> 6;
          const int r = seg & 63;
          const int b = r >> 3, f8 = (r & 7) * 8;
          const int sl = (st0 + slot) & 15;
          const int ofs = sl * 512 + b * 64 + f8;         // u16 units
          const int sw = ((ofs >> 3) ^ b) << 3;
          uint4 vv = *(const uint4*)((const u16*)xst + sw);
          const int tt = dir ? (511 - (st0 + slot)) : (st0 + slot);
          *(uint4*)(Xbf + ((size_t)tt * 32 + bg * 8 + b) * 512 + dir * 256 + s64 + f8) = vv;
        }
      } else {
        #pragma unroll
        for (int half = 0; half < 4; ++half) {
          const int seg = half * 256 + tid;     // 0..1023 segs of 16B
          const int slot = seg >> 7;
          const int rem = seg & 127;
          const int b = rem >> 4, f4 = (rem & 15) * 4;
          const int sl = (st0 + slot) & 15;
          const int ofs = sl * 512 + b * 64 + f4;         // u32 units
          const int sw = ((ofs >> 2) ^ b) << 2;
          uint4 vv = *(const uint4*)((const u32*)xst + sw);
          const int tt = dir ? (511 - (st0 + slot)) : (st0 + slot);
          *(uint4*)(Xu + ((size_t)tt * 32 + bg * 8 + b) * 512 + dir * 256 + s64 + f4) = vv;
        }
      }
    }
    // prefetch NEXT step's G — in the dead window; if the next poll waits
    // anyway (latency-bound), draining these inside the wait is free.
    {
      const int stn = (st < 511) ? st + 1 : 511;
      const int tn = dir ? (511 - stn) : stn;
      const u16* gp = gbase + (size_t)tn * 32 * 2048;
      gv0 = *(const u32*)(gp);
      gv1 = *(const u32*)(gp + 256);
      gv2 = *(const u32*)(gp + 512);
      gv3 = *(const u32*)(gp + 768);
    }
    // NO end-of-step barrier, NO store drain, NO flag.
  }
  // epilogue: dump last 8 staged steps (slots 8..15)
  __syncthreads();
  {
    const int st0 = 504;
    if (Xbf) {
      #pragma unroll
      for (int half = 0; half < 2; ++half) {
        const int seg = half * 256 + tid;
        const int slot = seg >> 6;
        const int r = seg & 63;
        const int b = r >> 3, f8 = (r & 7) * 8;
        const int sl = (st0 + slot) & 15;
        const int ofs = sl * 512 + b * 64 + f8;
        const int sw = ((ofs >> 3) ^ b) << 3;
        uint4 vv = *(const uint4*)((const u16*)xst + sw);
        const int tt = dir ? (511 - (st0 + slot)) : (st0 + slot);
        *(uint4*)(Xbf + ((size_t)tt * 32 + bg * 8 + b) * 512 + dir * 256 + s64 + f8) = vv;
      }
    } else {
      #pragma unroll
      for (int half = 0; half < 4; ++half) {
        const int seg = half * 256 + tid;
        const int slot = seg >> 7;
        const int rem = seg & 127;
        const int b = rem >> 4, f4 = (rem & 15) * 4;
        const int sl = (st0 + slot) & 15;
        const int ofs = sl * 512 + b * 64 + f4;
        const int sw = ((ofs >> 2) ^ b) << 2;
        uint4 vv = *(const uint4*)((const u32*)xst + sw);
        const int tt = dir ? (511 - (st0 + slot)) : (st0 + slot);
        *(uint4*)(Xu + ((size_t)tt * 32 + bg * 8 + b) * 512 + dir * 256 + s64 + f4) = vv;
      }
    }
  }
}

// ---------------- LayerNorm + classifier head; logits -> d_out+1 ----------------
// X2u: packed (bf16hi<<16|bf16lo) per element; decode = bf2f(hi)+bf2f(lo)
__global__ void head_k(const u32* __restrict__ X2u, const float* __restrict__ gamma,
                       const float* __restrict__ beta, const float* __restrict__ cw,
                       const float* __restrict__ cb, float* __restrict__ out) {
  __shared__ float red[9][64];
  const int m = blockIdx.x, lane = threadIdx.x;
  const int s = m >> 5, b = m & 31;
  const uint4* xp = (const uint4*)(X2u + (size_t)m * 512) + lane * 2;
  uint4 a0 = xp[0], a1 = xp[1];
  float x[8];
  x[0] = decode_hl(a0.x); x[1] = decode_hl(a0.y);
  x[2] = decode_hl(a0.z); x[3] = decode_hl(a0.w);
  x[4] = decode_hl(a1.x); x[5] = decode_hl(a1.y);
  x[6] = decode_hl(a1.z); x[7] = decode_hl(a1.w);
  float sm = 0.f, sq = 0.f;
  #pragma unroll
  for (int i = 0; i < 8; ++i) { sm += x[i]; sq += x[i] * x[i]; }
  #pragma unroll
  for (int off = 32; off > 0; off >>= 1) {
    sm += __shfl_xor(sm, off, 64);
    sq += __shfl_xor(sq, off, 64);
  }
  const float mu = sm * (1.0f / 512.0f);
  const float var = sq * (1.0f / 512.0f) - mu * mu;
  const float rs = rsqrtf(var + 1e-5f);
  const float4* gp = (const float4*)gamma + lane * 2;
  const float4* bp = (const float4*)beta + lane * 2;
  float4 g0 = gp[0], g1 = gp[1], be0 = bp[0], be1 = bp[1];
  float nv[8];
  nv[0] = (x[0] - mu) * rs * g0.x + be0.x;
  nv[1] = (x[1] - mu) * rs * g0.y + be0.y;
  nv[2] = (x[2] - mu) * rs * g0.z + be0.z;
  nv[3] = (x[3] - mu) * rs * g0.w + be0.w;
  nv[4] = (x[4] - mu) * rs * g1.x + be1.x;
  nv[5] = (x[5] - mu) * rs * g1.y + be1.y;
  nv[6] = (x[6] - mu) * rs * g1.z + be1.z;
  nv[7] = (x[7] - mu) * rs * g1.w + be1.w;
  #pragma unroll
  for (int c = 0; c < 9; ++c) {
    const float4* wp = (const float4*)(cw + (size_t)c * 512) + lane * 2;
    float4 w0 = wp[0], w1 = wp[1];
    red[c][lane] = nv[0]*w0.x + nv[1]*w0.y + nv[2]*w0.z + nv[3]*w0.w
                 + nv[4]*w1.x + nv[5]*w1.y + nv[6]*w1.z + nv[7]*w1.w;
  }
  __syncthreads();
  if (lane < 9) {
    float t = 0.f;
    for (int i = 0; i < 64; ++i) t += red[lane][i];
    out[1 + ((size_t)b * 512 + s) * 9 + lane] = t + cb[lane];
  }
}

// ---------------- CRF NLL: one wave per batch element ----------------
__global__ void crf_k(const float* __restrict__ logits, const int* __restrict__ labels,
                      const int* __restrict__ lens, const float* __restrict__ tr,
                      float* __restrict__ loss) {
  const int b = blockIdx.x, lane = threadIdx.x;
  const int len = lens[b];
  float trj[9];
  #pragma unroll
  for (int i = 0; i < 9; ++i) trj[i] = 0.f;
  if (lane < 9) {
    #pragma unroll
    for (int i = 0; i < 9; ++i) trj[i] = tr[i * 11 + lane];
  }
  float alpha = -1e30f;
  if (lane < 9) alpha = tr[9 * 11 + lane] + logits[(size_t)b * 512 * 9 + lane];
  for (int t = 1; t < len; ++t) {
    float e = (lane < 9) ? logits[((size_t)b * 512 + t) * 9 + lane] : 0.f;
    float v[9];
    float mx = -1e30f;
    #pragma unroll
    for (int i = 0; i < 9; ++i) {
      v[i] = __shfl(alpha, i, 64) + trj[i];
      mx = fmaxf(mx, v[i]);
    }
    float ss = 0.f;
    #pragma unroll
    for (int i = 0; i < 9; ++i) ss += __expf(v[i] - mx);
    float na = mx + __logf(ss) + e;
    if (lane < 9) alpha = na;
  }
  float fin = (lane < 9) ? alpha + tr[lane * 11 + 10] : -1e30f;
  float mx = fin;
  #pragma unroll
  for (int off = 8; off > 0; off >>= 1) mx = fmaxf(mx, __shfl_xor(mx, off, 64));
  float es = (lane < 9) ? __expf(fin - mx) : 0.f;
  #pragma unroll
  for (int off = 8; off > 0; off >>= 1) es += __shfl_xor(es, off, 64);
  const float logZ = mx + __logf(es);
  float emit = 0.f, ts = 0.f;
  for (int t = lane; t < len; t += 64) {
    int y = labels[b * 512 + t];
    emit += logits[((size_t)b * 512 + t) * 9 + y];
  }
  for (int t = 1 + lane; t < len; t += 64) {
    int y0 = labels[b * 512 + t - 1], y1 = labels[b * 512 + t];
    ts += tr[y0 * 11 + y1];
  }
  #pragma unroll
  for (int off = 32; off > 0; off >>= 1) {
    emit += __shfl_xor(emit, off, 64);
    ts += __shfl_xor(ts, off, 64);
  }
  if (lane == 0) {
    int y0 = labels[b * 512], yl = labels[b * 512 + len - 1];
    float gold = emit + ts + tr[9 * 11 + y0] + tr[yl * 11 + 10];
    atomicAdd(loss, (logZ - gold) * (1.0f / 32.0f));
  }
}

extern "C" void kernel_launch(void* const* d_in, const int* in_sizes, int n_in,
                              void* d_out, int out_size, void* d_ws, size_t ws_size,
                              hipStream_t stream) {
  const int* ids = (const int*)d_in[0];
  const int* amask = (const int*)d_in[1];
  const int* lens = (const int*)d_in[2];
  const int* labels = (const int*)d_in[3];
  const float* emb = (const float*)d_in[4];
  const float* w_ih = (const float*)d_in[5];
  const float* w_hh = (const float*)d_in[6];
  const float* b_ih = (const float*)d_in[7];
  const float* b_hh = (const float*)d_in[8];
  const float* gamma = (const float*)d_in[9];
  const float* beta = (const float*)d_in[10];
  const float* cw = (const float*)d_in[11];
  const float* cb = (const float*)d_in[12];
  const float* tr = (const float*)d_in[13];
  (void)in_sizes; (void)n_in; (void)out_size;

  if (ws_size < WS_NEEDED) return;  // workspace too small -> clean failure

  char* p = (char*)d_ws;
  u16* X0 = (u16*)p;      p += (size_t)16384 * 512 * 2;        // 16.78 MB
  u16* Wbf = (u16*)p;     p += (size_t)2 * 2 * 1024 * 512 * 2; // 4.19 MB
  u16* G = (u16*)p;       p += (size_t)16384 * 2048 * 2;       // 67.1 MB
  u16* X1 = (u16*)p;      p += (size_t)16384 * 512 * 2;        // 16.78 MB
  u32* X2u = (u32*)p;     p += (size_t)16384 * 512 * 4;        // 33.55 MB
  float* out = (float*)d_out;

  // Exchange replica buffers (512 KB each set: 8 grps x 4 reps x 4096 u32),
  // carved from DEAD workspace regions:
  //  layer0: head of X2u (free until rec1 overwrites all of X2u)
  //  layer1: head of X0  (dead after gemm0 consumes it)
  u32* Hb4_l0 = X2u;
  u32* Hb4_l1 = (u32*)X0;

  prep_k<<<16384, 64, 0, stream>>>(ids, amask, emb, X0);
  conv_k<<<1024, 256, 0, stream>>>(w_ih, Wbf, 262144);
  zero_k<<<1, 64, 0, stream>>>(out);
  poison_k<<<128, 256, 0, stream>>>(Hb4_l0);   // 512 KB of 0xAAAA
  // Layer 0 (tags 1..512)
  gemm_k<<<dim3(256, 32), 256, 0, stream>>>(X0, Wbf, b_ih, b_hh, G);
  poison_k<<<128, 256, 0, stream>>>(Hb4_l1);   // X0 dead after gemm0
  rec_k<<<32, 256, 0, stream>>>(G, w_hh, Hb4_l0, 0, X1, nullptr);
  // Layer 1 (tags 1025..1536 — never aliases layer 0 or 0xAAAA poison)
  gemm_k<<<dim3(256, 32), 256, 0, stream>>>(X1, Wbf + 2 * 1024 * 512,
                                            b_ih + 2048, b_hh + 2048, G);
  rec_k<<<32, 256, 0, stream>>>(G, w_hh + 2 * 1024 * 256, Hb4_l1, 1024,
                                nullptr, X2u);
  // Head + CRF
  head_k<<<16384, 64, 0, stream>>>(X2u, gamma, beta, cw, cb, out);
  crf_k<<<32, 64, 0, stream>>>(out + 1, labels, lens, tr, out);
}